// Round 4
// baseline (442.242 us; speedup 1.0000x reference)
//
#include <hip/hip_runtime.h>
#include <hip/hip_bf16.h>
#include <stdint.h>

// QuantizedLinear: out_f32[512,16384] = x_f32[512,4096] @ (qw_i32 * scales)^T + bias
// dtypes (verified round 3): x fp32, qw int32, scales fp32, bias fp32, out fp32.
//
// Round-11: break PHASE LOCKSTEP with 2 independent blocks per CU.
// Post-mortem r7/r8: nodrain barrier AND deep prefetch+early-write both
// NEUTRAL (417/418 -> 422). Model revision: with one 16-wave block per CU,
// the per-iter barrier locksteps the whole CU -- stage phase and compute
// phase alternate globally, so LDS / MFMA / HBM / L2 pipes each get an
// exclusive time slice (measured per-iter ~= SUM of pipes, 11k cyc). Fixes
// that reorder work INSIDE the lockstep can't help -- which is exactly what
// we observed twice.
// Fix (m114 mechanism): two CO-RESIDENT 512-thread blocks per CU (M-split).
// Independent barriers drift out of phase; block A computes while block B
// stages -> time -> max(pipes). No new sync structure: the per-iter dataflow
// is the PROVEN round-7 one (dequant -> write -> single lgkm-only barrier ->
// compute), just 8 waves covering a 256-row half.
//  - grid 512 = (NN/64 slabs) x (2 M-halves); block 512 thr = 8 waves.
//  - __launch_bounds__(512,4): VGPR cap 128 -> 16 waves/CU = 2 blocks/CU.
//    Register budget ~120: acc 32 + A single-buf 32 + qv prefetch 16 + misc.
//    (A reg-double-buffer dropped -- partner block hides L2 latency now.)
//  - producer: each thread dequants rows r and r+32 of the 64-row slab.
//  - qw slab read by both M-half blocks: partner re-read hits L3 (256 MB).
// Unchanged: fragment-order swizzled LDS (conflict-free), packed-x prepass,
// 1-deep qw prefetch, lgkm-only barrier, epilogue.

#define MM 512
#define NN 16384
#define KK 4096
#define BN 64
#define BK 128
#define NKB (KK / BK)   // 32

typedef __bf16 bf16x8 __attribute__((ext_vector_type(8)));
typedef float floatx4 __attribute__((ext_vector_type(4)));

__device__ __forceinline__ void barrier_nodrain() {
    // LDS handoff needs lgkmcnt(0); deliberately NO vmcnt drain.
    asm volatile("s_waitcnt lgkmcnt(0)\n\ts_barrier" ::: "memory");
}

__device__ __forceinline__ unsigned int pk_bf16_rtn(float lo, float hi) {
    __hip_bfloat162 h = __float22bfloat162_rn(float2{lo, hi});
    return *reinterpret_cast<unsigned int*>(&h);
}

__device__ __forceinline__ uint4 deq8(const int4 q0, const int4 q1, const float s) {
    uint4 u;
    u.x = pk_bf16_rtn((float)q0.x * s, (float)q0.y * s);
    u.y = pk_bf16_rtn((float)q0.z * s, (float)q0.w * s);
    u.z = pk_bf16_rtn((float)q1.x * s, (float)q1.y * s);
    u.w = pk_bf16_rtn((float)q1.z * s, (float)q1.w * s);
    return u;
}

// ---- prepass: x fp32 -> bf16, packed in MFMA A-fragment order ----
// xp element index: (((kb*4 + ks)*32 + mt)*64 + lane)*8,
//   holding x[mt*16 + (lane&15)][kb*128 + ks*32 + (lane>>4)*8 .. +8]
__global__ __launch_bounds__(256) void pack_x(const float* __restrict__ x,
                                              unsigned short* __restrict__ xp) {
    const int t    = blockIdx.x * 256 + threadIdx.x;   // 0..262143
    const int lane = t & 63;
    const int mt   = (t >> 6) & 31;
    const int ks   = (t >> 11) & 3;
    const int kb   = t >> 13;
    const int m    = mt * 16 + (lane & 15);
    const int k    = kb * 128 + ks * 32 + (lane >> 4) * 8;
    const float* px = x + (size_t)m * KK + k;
    const float4 a = *(const float4*)px;
    const float4 b = *(const float4*)(px + 4);
    uint4 o;
    o.x = pk_bf16_rtn(a.x, a.y);
    o.y = pk_bf16_rtn(a.z, a.w);
    o.z = pk_bf16_rtn(b.x, b.y);
    o.w = pk_bf16_rtn(b.z, b.w);
    *(uint4*)(xp + (size_t)t * 8) = o;   // fully coalesced 16B/thread
}

template <bool PRE>
__global__ __launch_bounds__(512, 4) void qlin_gemm(
    const float* __restrict__ xf,               // fp32 x (fallback path)
    const unsigned short* __restrict__ xp,      // packed bf16 x (prepass path)
    const int* __restrict__ qw,                 // int32 [16384,4096]
    const float* __restrict__ scales,           // fp32 [16384,64]
    const float* __restrict__ bias,             // fp32 [16384]
    float* __restrict__ out)                    // fp32 [512,16384]
{
    __shared__ unsigned short sB[2][BN * BK];   // fragment-ordered + swizzled, 2 x 16 KB

    const int t    = threadIdx.x;     // 0..511
    const int lane = t & 63;
    const int w    = t >> 6;          // wave 0..7 -> M strip [h*256 + w*32, +32)
    const int ln   = lane & 15;
    const int quad = lane >> 4;
    const int h    = blockIdx.x & 1;          // M half: rows [h*256, h*256+256)
    const int n0   = (blockIdx.x >> 1) * BN;  // column slab

    // ---- producer mapping: thread t -> qw rows (r, r+32), k-octet (t&15) ----
    const int r    = t >> 4;          // 0..31
    const int oct  = t & 15;
    const int ksp  = oct >> 2;        // frag k-slice 0..3
    const int jp   = r >> 4;          // frag col-tile 0..1 (row r); row r+32 -> jp+2
    const int ldst = (((oct & 3) << 4) | (r & 15)) ^ (ksp << 1);   // swizzled frag lane
    const int woff = ((ksp * 4 + jp) * 64 + ldst) * 8;             // row r+32 at +1024
    const int* qp0   = qw + (size_t)(n0 + r) * KK + oct * 8;
    const int* qp1   = qp0 + (size_t)32 * KK;
    const float* sp0 = scales + (size_t)(n0 + r) * 64 + (oct >> 3);
    const float* sp1 = sp0 + 32 * 64;

    floatx4 acc[2][4];
#pragma unroll
    for (int i = 0; i < 2; ++i)
#pragma unroll
        for (int j = 0; j < 4; ++j)
            acc[i][j] = (floatx4)0.0f;

    // ---- prologue: qw slab 0 in flight ----
    int4 qa0 = *(const int4*)(qp0);
    int4 qa1 = *(const int4*)(qp0 + 4);
    int4 qb0 = *(const int4*)(qp1);
    int4 qb1 = *(const int4*)(qp1 + 4);
    float sa = sp0[0];
    float sc = sp1[0];

    bf16x8 a[4][2];   // A single-buffer (partner block hides the L2 latency)

    for (int kb = 0; kb < NKB; ++kb) {
        unsigned short* sbuf = sB[kb & 1];

        // ---- A-loads for kb issued FIRST (younger than the qv waited on
        // below -> dequant's vmcnt wait does not drain them).
        if constexpr (PRE) {
            const unsigned short* xpb = xp + (size_t)kb * (4 * 32 * 64 * 8);
#pragma unroll
            for (int ks = 0; ks < 4; ++ks) {
                const unsigned short* ap =
                    xpb + (size_t)((ks * 32 + h * 16 + w * 2) * 64 + lane) * 8;
                a[ks][0] = *(const bf16x8*)(ap);
                a[ks][1] = *(const bf16x8*)(ap + 512);
            }
        }

        // ---- dequant slab kb (qv issued one iter ago) -> LDS, 2 rows/thread
        {
            uint4 u0 = deq8(qa0, qa1, sa);
            uint4 u1 = deq8(qb0, qb1, sc);
            *(uint4*)(sbuf + woff)        = u0;
            *(uint4*)(sbuf + woff + 1024) = u1;
        }

        // ---- qw slab kb+1 prefetch (1-deep) ----
        if (kb + 1 < NKB) {
            qa0 = *(const int4*)(qp0 + (size_t)(kb + 1) * BK);
            qa1 = *(const int4*)(qp0 + (size_t)(kb + 1) * BK + 4);
            qb0 = *(const int4*)(qp1 + (size_t)(kb + 1) * BK);
            qb1 = *(const int4*)(qp1 + (size_t)(kb + 1) * BK + 4);
            sa = sp0[(size_t)(kb + 1) * 2];
            sc = sp1[(size_t)(kb + 1) * 2];
        }

        // ---- publish slab kb (lgkm-only barrier; vmem streams stay in flight)
        barrier_nodrain();

        // ---- compute kb from LDS B + register A (j-paired: 8 live B VGPRs) ----
#pragma unroll
        for (int ks = 0; ks < 4; ++ks) {
            bf16x8 a0, a1;
            if constexpr (PRE) {
                a0 = a[ks][0];
                a1 = a[ks][1];
            } else {
                const int k = kb * BK + ks * 32 + quad * 8;
#pragma unroll
                for (int i = 0; i < 2; ++i) {
                    const float* px =
                        xf + (size_t)(h * 256 + w * 32 + i * 16 + ln) * KK + k;
                    const float4 f0 = *(const float4*)px;
                    const float4 f1 = *(const float4*)(px + 4);
                    uint4 ua;
                    ua.x = pk_bf16_rtn(f0.x, f0.y);
                    ua.y = pk_bf16_rtn(f0.z, f0.w);
                    ua.z = pk_bf16_rtn(f1.x, f1.y);
                    ua.w = pk_bf16_rtn(f1.z, f1.w);
                    if (i == 0) a0 = *(bf16x8*)&ua; else a1 = *(bf16x8*)&ua;
                }
            }
            const int sl = lane ^ (ks << 1);
#pragma unroll
            for (int jj = 0; jj < 4; jj += 2) {
                bf16x8 b0 = *(const bf16x8*)(sbuf + ((ks * 4 + jj) * 64 + sl) * 8);
                bf16x8 b1 = *(const bf16x8*)(sbuf + ((ks * 4 + jj + 1) * 64 + sl) * 8);
                acc[0][jj]     = __builtin_amdgcn_mfma_f32_16x16x32_bf16(a0, b0, acc[0][jj], 0, 0, 0);
                acc[1][jj]     = __builtin_amdgcn_mfma_f32_16x16x32_bf16(a1, b0, acc[1][jj], 0, 0, 0);
                acc[0][jj + 1] = __builtin_amdgcn_mfma_f32_16x16x32_bf16(a0, b1, acc[0][jj + 1], 0, 0, 0);
                acc[1][jj + 1] = __builtin_amdgcn_mfma_f32_16x16x32_bf16(a1, b1, acc[1][jj + 1], 0, 0, 0);
            }
        }
        // no trailing barrier needed: iter kb+1 writes the OTHER LDS buffer,
        // and the mid-iter barrier (lgkmcnt(0)) of iter kb+1 already separates
        // its write of buf[cur^1] from THIS iter's reads... (reads drained per
        // wave at that barrier before any wave proceeds to iter kb+2's write
        // of buf[cur]).
    }

    // ---- epilogue: + bias, store fp32 ----
#pragma unroll
    for (int j = 0; j < 4; ++j) {
        const int n = n0 + j * 16 + ln;
        const float bv = bias[n];
#pragma unroll
        for (int i = 0; i < 2; ++i) {
            const int mbase = h * 256 + w * 32 + i * 16 + quad * 4;
#pragma unroll
            for (int rr = 0; rr < 4; ++rr)
                out[(size_t)(mbase + rr) * NN + n] = acc[i][j][rr] + bv;
        }
    }
}

extern "C" void kernel_launch(void* const* d_in, const int* in_sizes, int n_in,
                              void* d_out, int out_size, void* d_ws, size_t ws_size,
                              hipStream_t stream) {
    const float* x    = (const float*)d_in[0];
    const int* qw     = (const int*)d_in[1];
    const float* scl  = (const float*)d_in[2];
    const float* bias = (const float*)d_in[3];
    float* out        = (float*)d_out;

    dim3 grid(NN / BN * 2);   // 512 blocks: 256 column slabs x 2 M-halves
    dim3 block(512);          // 8 waves -> 2 co-resident blocks per CU

    if (ws_size >= (size_t)MM * KK * sizeof(unsigned short)) {
        unsigned short* xp = (unsigned short*)d_ws;
        pack_x<<<dim3(MM * KK / (256 * 8)), dim3(256), 0, stream>>>(x, xp);
        qlin_gemm<true><<<grid, block, 0, stream>>>(x, xp, qw, scl, bias, out);
    } else {
        qlin_gemm<false><<<grid, block, 0, stream>>>(x, nullptr, qw, scl, bias, out);
    }
}

// Round 5
// 437.405 us; speedup vs baseline: 1.0111x; 1.0111x over previous
//
#include <hip/hip_runtime.h>
#include <hip/hip_bf16.h>
#include <stdint.h>

// QuantizedLinear: out_f32[512,16384] = x_f32[512,4096] @ (qw_i32 * scales)^T + bias
// dtypes (verified round 3): x fp32, qw int32, scales fp32, bias fp32, out fp32.
//
// Round-12: 4-phase interleaved schedule with counted vmcnt (T3+T4 port).
// Round-11 post-mortem (first real gemm counters): 167-172us, MfmaUtil 16%,
// VALUBusy 13%, HBM 24%, Occ 35% -- ALL pipes idle; per-iter 12.6k cyc vs
// ~3.3k max pipe. 2 blocks/CU phase-locked (convoy), didn't anti-phase.
// This is the guide's measured 2-phase wall (m233: stage+vmcnt+barrier = 72%
// of critical path; single-piece fixes null -- matches r7/r8/r11 exactly).
// Exit per m196/m198/m218: phase-split the K-step and keep loads in flight
// with counted (never 0) vmcnt:
//   phase p in 0..3 of iter kb:
//     [stage slice: p0 deq+write row r of slab kb+1, p1 deq+write row r+32,
//      p3 issue qw(kb+2) BEFORE a3-refill so dequant waits vmcnt(2) not 0]
//     ds_read B frags (ks=p); lgkm-only barrier; sched_barrier(0) [rule 18];
//     setprio(1) 8x MFMA setprio(0) [T5, now has role-split];
//     refill a[p] IN PLACE for kb+1 (dead after its MFMAs -> no dbuf, single
//     A buffer, ~full iter of latency cover, VGPR ~115 < 128 cap).
// Staging slab kb+1 into buf[cur^1] during iter kb is WAR-safe: iter kb-1's
// readers of that buffer drained at its P3 lgkm-barrier. RAW-safe: writes
// published by P0/P1 barriers, consumed next iter.
// Unchanged from r11 (passed, absmax 0.125): producer mapping, swizzle,
// deq8, pack_x prepass, epilogue, grid 512 x 512thr (2 blocks/CU).

#define MM 512
#define NN 16384
#define KK 4096
#define BN 64
#define BK 128
#define NKB (KK / BK)   // 32

typedef __bf16 bf16x8 __attribute__((ext_vector_type(8)));
typedef float floatx4 __attribute__((ext_vector_type(4)));

__device__ __forceinline__ void barrier_nodrain() {
    // LDS handoff needs lgkmcnt(0) (covers this phase's ds_write AND ds_read);
    // deliberately NO vmcnt drain -- global streams stay in flight.
    asm volatile("s_waitcnt lgkmcnt(0)\n\ts_barrier" ::: "memory");
}

__device__ __forceinline__ unsigned int pk_bf16_rtn(float lo, float hi) {
    __hip_bfloat162 h = __float22bfloat162_rn(float2{lo, hi});
    return *reinterpret_cast<unsigned int*>(&h);
}

__device__ __forceinline__ uint4 deq8(const int4 q0, const int4 q1, const float s) {
    uint4 u;
    u.x = pk_bf16_rtn((float)q0.x * s, (float)q0.y * s);
    u.y = pk_bf16_rtn((float)q0.z * s, (float)q0.w * s);
    u.z = pk_bf16_rtn((float)q1.x * s, (float)q1.y * s);
    u.w = pk_bf16_rtn((float)q1.z * s, (float)q1.w * s);
    return u;
}

// ---- prepass: x fp32 -> bf16, packed in MFMA A-fragment order ----
// xp element index: (((kb*4 + ks)*32 + mt)*64 + lane)*8,
//   holding x[mt*16 + (lane&15)][kb*128 + ks*32 + (lane>>4)*8 .. +8]
__global__ __launch_bounds__(256) void pack_x(const float* __restrict__ x,
                                              unsigned short* __restrict__ xp) {
    const int t    = blockIdx.x * 256 + threadIdx.x;   // 0..262143
    const int lane = t & 63;
    const int mt   = (t >> 6) & 31;
    const int ks   = (t >> 11) & 3;
    const int kb   = t >> 13;
    const int m    = mt * 16 + (lane & 15);
    const int k    = kb * 128 + ks * 32 + (lane >> 4) * 8;
    const float* px = x + (size_t)m * KK + k;
    const float4 a = *(const float4*)px;
    const float4 b = *(const float4*)(px + 4);
    uint4 o;
    o.x = pk_bf16_rtn(a.x, a.y);
    o.y = pk_bf16_rtn(a.z, a.w);
    o.z = pk_bf16_rtn(b.x, b.y);
    o.w = pk_bf16_rtn(b.z, b.w);
    *(uint4*)(xp + (size_t)t * 8) = o;   // fully coalesced 16B/thread
}

template <bool PRE>
__global__ __launch_bounds__(512, 4) void qlin_gemm(
    const float* __restrict__ xf,               // fp32 x (fallback path)
    const unsigned short* __restrict__ xp,      // packed bf16 x (prepass path)
    const int* __restrict__ qw,                 // int32 [16384,4096]
    const float* __restrict__ scales,           // fp32 [16384,64]
    const float* __restrict__ bias,             // fp32 [16384]
    float* __restrict__ out)                    // fp32 [512,16384]
{
    __shared__ unsigned short sB[2][BN * BK];   // fragment-ordered + swizzled, 2 x 16 KB

    const int t    = threadIdx.x;     // 0..511
    const int lane = t & 63;
    const int w    = t >> 6;          // wave 0..7 -> M strip [h*256 + w*32, +32)
    const int ln   = lane & 15;
    const int quad = lane >> 4;
    const int h    = blockIdx.x & 1;          // M half: rows [h*256, h*256+256)
    const int n0   = (blockIdx.x >> 1) * BN;  // column slab

    // ---- producer mapping: thread t -> qw rows (r, r+32), k-octet (t&15) ----
    const int r    = t >> 4;          // 0..31
    const int oct  = t & 15;
    const int ksp  = oct >> 2;        // frag k-slice 0..3
    const int jp   = r >> 4;          // frag col-tile 0..1 (row r); row r+32 -> jp+2
    const int ldst = (((oct & 3) << 4) | (r & 15)) ^ (ksp << 1);   // swizzled frag lane
    const int woff = ((ksp * 4 + jp) * 64 + ldst) * 8;             // row r+32 at +1024
    const int* qp0   = qw + (size_t)(n0 + r) * KK + oct * 8;
    const int* qp1   = qp0 + (size_t)32 * KK;
    const float* sp0 = scales + (size_t)(n0 + r) * 64 + (oct >> 3);
    const float* sp1 = sp0 + 32 * 64;

    floatx4 acc[2][4];
#pragma unroll
    for (int i = 0; i < 2; ++i)
#pragma unroll
        for (int j = 0; j < 4; ++j)
            acc[i][j] = (floatx4)0.0f;

    // ---- prologue: stage slab 0 into buf0, qw(1) + A(0) in flight ----
    int4 qa0 = *(const int4*)(qp0);
    int4 qa1 = *(const int4*)(qp0 + 4);
    int4 qb0 = *(const int4*)(qp1);
    int4 qb1 = *(const int4*)(qp1 + 4);
    float sa = sp0[0];
    float sc = sp1[0];

    bf16x8 a[4][2];   // A single-buffer; a[p] refilled in place after phase p

    {
        uint4 u0 = deq8(qa0, qa1, sa);
        uint4 u1 = deq8(qb0, qb1, sc);
        *(uint4*)(sB[0] + woff)        = u0;
        *(uint4*)(sB[0] + woff + 1024) = u1;
    }
    // qw slab 1 (consumed by iter-0 staging of slab 1)
    qa0 = *(const int4*)(qp0 + BK);
    qa1 = *(const int4*)(qp0 + BK + 4);
    qb0 = *(const int4*)(qp1 + BK);
    qb1 = *(const int4*)(qp1 + BK + 4);
    sa = sp0[2];
    sc = sp1[2];
    if constexpr (PRE) {
#pragma unroll
        for (int p = 0; p < 4; ++p) {
            const unsigned short* ap =
                xp + (size_t)((p * 32 + h * 16 + w * 2) * 64 + lane) * 8;
            a[p][0] = *(const bf16x8*)(ap);
            a[p][1] = *(const bf16x8*)(ap + 512);
        }
    }
    barrier_nodrain();   // publish slab 0

    // ---- main loop: 4 phases per K-step ----
    for (int kb = 0; kb < NKB; ++kb) {
        const int cur = kb & 1;
        const unsigned short* sbR = sB[cur];
        unsigned short* sbW       = sB[cur ^ 1];
        const bool stage = (kb + 1 < NKB);

#pragma unroll
        for (int p = 0; p < 4; ++p) {
            // ---- stage-issue slice for this phase (pre-barrier region) ----
            if (p == 0 && stage) {
                uint4 u0 = deq8(qa0, qa1, sa);      // qw(kb+1), issued iter kb-1 P3
                *(uint4*)(sbW + woff) = u0;         // WAR-safe: readers drained @kb-1 P3
            }
            if (p == 1 && stage) {
                uint4 u1 = deq8(qb0, qb1, sc);
                *(uint4*)(sbW + woff + 1024) = u1;
            }
            if (p == 3 && kb + 2 < NKB) {
                // qw(kb+2) issued BEFORE the a[3] refill below -> next iter's
                // dequant waits vmcnt(2), never draining the A stream.
                qa0 = *(const int4*)(qp0 + (size_t)(kb + 2) * BK);
                qa1 = *(const int4*)(qp0 + (size_t)(kb + 2) * BK + 4);
                qb0 = *(const int4*)(qp1 + (size_t)(kb + 2) * BK);
                qb1 = *(const int4*)(qp1 + (size_t)(kb + 2) * BK + 4);
                sa = sp0[(size_t)(kb + 2) * 2];
                sc = sp1[(size_t)(kb + 2) * 2];
            }

            // ---- B fragments for ks = p ----
            const int sl = lane ^ (p << 1);
            bf16x8 b0 = *(const bf16x8*)(sbR + ((p * 4 + 0) * 64 + sl) * 8);
            bf16x8 b1 = *(const bf16x8*)(sbR + ((p * 4 + 1) * 64 + sl) * 8);
            bf16x8 b2 = *(const bf16x8*)(sbR + ((p * 4 + 2) * 64 + sl) * 8);
            bf16x8 b3 = *(const bf16x8*)(sbR + ((p * 4 + 3) * 64 + sl) * 8);

            barrier_nodrain();                      // lgkm(0): reads landed, writes published
            __builtin_amdgcn_sched_barrier(0);      // rule 18: pin MFMAs after the wait

            bf16x8 a0, a1;
            if constexpr (PRE) {
                a0 = a[p][0];
                a1 = a[p][1];
            } else {
                const int k = kb * BK + p * 32 + quad * 8;
#pragma unroll
                for (int i = 0; i < 2; ++i) {
                    const float* px =
                        xf + (size_t)(h * 256 + w * 32 + i * 16 + ln) * KK + k;
                    const float4 f0 = *(const float4*)px;
                    const float4 f1 = *(const float4*)(px + 4);
                    uint4 ua;
                    ua.x = pk_bf16_rtn(f0.x, f0.y);
                    ua.y = pk_bf16_rtn(f0.z, f0.w);
                    ua.z = pk_bf16_rtn(f1.x, f1.y);
                    ua.w = pk_bf16_rtn(f1.z, f1.w);
                    if (i == 0) a0 = *(bf16x8*)&ua; else a1 = *(bf16x8*)&ua;
                }
            }

            __builtin_amdgcn_s_setprio(1);          // T5: favor the MFMA cluster
            acc[0][0] = __builtin_amdgcn_mfma_f32_16x16x32_bf16(a0, b0, acc[0][0], 0, 0, 0);
            acc[1][0] = __builtin_amdgcn_mfma_f32_16x16x32_bf16(a1, b0, acc[1][0], 0, 0, 0);
            acc[0][1] = __builtin_amdgcn_mfma_f32_16x16x32_bf16(a0, b1, acc[0][1], 0, 0, 0);
            acc[1][1] = __builtin_amdgcn_mfma_f32_16x16x32_bf16(a1, b1, acc[1][1], 0, 0, 0);
            acc[0][2] = __builtin_amdgcn_mfma_f32_16x16x32_bf16(a0, b2, acc[0][2], 0, 0, 0);
            acc[1][2] = __builtin_amdgcn_mfma_f32_16x16x32_bf16(a1, b2, acc[1][2], 0, 0, 0);
            acc[0][3] = __builtin_amdgcn_mfma_f32_16x16x32_bf16(a0, b3, acc[0][3], 0, 0, 0);
            acc[1][3] = __builtin_amdgcn_mfma_f32_16x16x32_bf16(a1, b3, acc[1][3], 0, 0, 0);
            __builtin_amdgcn_s_setprio(0);

            // ---- refill a[p] in place for iter kb+1 (a[p] dead after MFMAs;
            // ~a full iteration of latency cover before next use) ----
            if constexpr (PRE) {
                if (stage) {
                    const unsigned short* ap =
                        xp + (size_t)(kb + 1) * (4 * 32 * 64 * 8)
                           + (size_t)((p * 32 + h * 16 + w * 2) * 64 + lane) * 8;
                    a[p][0] = *(const bf16x8*)(ap);
                    a[p][1] = *(const bf16x8*)(ap + 512);
                }
            }
        }
    }

    // ---- epilogue: + bias, store fp32 ----
#pragma unroll
    for (int j = 0; j < 4; ++j) {
        const int n = n0 + j * 16 + ln;
        const float bv = bias[n];
#pragma unroll
        for (int i = 0; i < 2; ++i) {
            const int mbase = h * 256 + w * 32 + i * 16 + quad * 4;
#pragma unroll
            for (int rr = 0; rr < 4; ++rr)
                out[(size_t)(mbase + rr) * NN + n] = acc[i][j][rr] + bv;
        }
    }
}

extern "C" void kernel_launch(void* const* d_in, const int* in_sizes, int n_in,
                              void* d_out, int out_size, void* d_ws, size_t ws_size,
                              hipStream_t stream) {
    const float* x    = (const float*)d_in[0];
    const int* qw     = (const int*)d_in[1];
    const float* scl  = (const float*)d_in[2];
    const float* bias = (const float*)d_in[3];
    float* out        = (float*)d_out;

    dim3 grid(NN / BN * 2);   // 512 blocks: 256 column slabs x 2 M-halves
    dim3 block(512);          // 8 waves -> 2 co-resident blocks per CU

    if (ws_size >= (size_t)MM * KK * sizeof(unsigned short)) {
        unsigned short* xp = (unsigned short*)d_ws;
        pack_x<<<dim3(MM * KK / (256 * 8)), dim3(256), 0, stream>>>(x, xp);
        qlin_gemm<true><<<grid, block, 0, stream>>>(x, xp, qw, scl, bias, out);
    } else {
        qlin_gemm<false><<<grid, block, 0, stream>>>(x, nullptr, qw, scl, bias, out);
    }
}